// Round 1
// baseline (537.462 us; speedup 1.0000x reference)
//
#include <hip/hip_runtime.h>
#include <cstdint>

typedef __bf16 bf16x8 __attribute__((ext_vector_type(8)));
typedef float f32x4 __attribute__((ext_vector_type(4)));
typedef unsigned short u16;

#define B_ 4
#define T_ 2048
#define D_ 1024
#define H_ 16
#define HD_ 64
#define M_ (B_*T_)

__device__ __forceinline__ u16 f2bf(float f) {
  union { float f; uint32_t u; } x; x.f = f;
  uint32_t u = x.u;
  uint32_t r = (u + 0x7FFFu + ((u >> 16) & 1u)) >> 16;
  return (u16)r;
}

__device__ __forceinline__ bf16x8 ld8(const u16* p) {
  return *(const bf16x8*)p;
}

__global__ void cvt_bf16(const float* __restrict__ src, u16* __restrict__ dst, int n) {
  int i = (blockIdx.x * 256 + threadIdx.x) * 4;
  if (i < n) {
    float4 v = *(const float4*)(src + i);
    ushort4 o;
    o.x = f2bf(v.x); o.y = f2bf(v.y); o.z = f2bf(v.z); o.w = f2bf(v.w);
    *(ushort4*)(dst + i) = o;
  }
}

// C = A(MxK) * Bw(NxK)^T + bias.  M=8192, N=K=1024.
// mode 0: Q -> [B,H,T,HD] bf16; mode 1: K -> same; mode 2: V -> [B,H,HD,T] bf16 (LDS bounce);
// mode 3: fp32 out [M,N].
__global__ __launch_bounds__(256)
void gemm_bt(const u16* __restrict__ A, const u16* __restrict__ Bw,
             const float* __restrict__ bias, void* __restrict__ Cout, int mode) {
  const int K = D_, N = D_;
  __shared__ u16 As[64 * 40];
  __shared__ u16 Bs[64 * 40];
  __shared__ u16 Cs[64 * 72];
  int tid = threadIdx.x;
  int m0 = blockIdx.y * 64, n0 = blockIdx.x * 64;
  int wv = tid >> 6, lane = tid & 63, lanem = lane & 15, quad = lane >> 4;
  int wm = (wv >> 1) * 32, wn = (wv & 1) * 32;
  int sr = tid >> 2, sc = (tid & 3) * 8;
  const u16* Ag = A + (size_t)(m0 + sr) * K + sc;
  const u16* Bg = Bw + (size_t)(n0 + sr) * K + sc;
  u16* Asp = &As[sr * 40 + sc];
  u16* Bsp = &Bs[sr * 40 + sc];

  f32x4 acc[2][2];
#pragma unroll
  for (int mi = 0; mi < 2; ++mi)
#pragma unroll
    for (int ni = 0; ni < 2; ++ni)
      acc[mi][ni] = (f32x4){0.f, 0.f, 0.f, 0.f};

  for (int k0 = 0; k0 < K; k0 += 32) {
    *(uint4*)Asp = *(const uint4*)(Ag + k0);
    *(uint4*)Bsp = *(const uint4*)(Bg + k0);
    __syncthreads();
    bf16x8 a0 = ld8(&As[(wm + lanem) * 40 + quad * 8]);
    bf16x8 a1 = ld8(&As[(wm + 16 + lanem) * 40 + quad * 8]);
    bf16x8 b0 = ld8(&Bs[(wn + lanem) * 40 + quad * 8]);
    bf16x8 b1 = ld8(&Bs[(wn + 16 + lanem) * 40 + quad * 8]);
    acc[0][0] = __builtin_amdgcn_mfma_f32_16x16x32_bf16(a0, b0, acc[0][0], 0, 0, 0);
    acc[0][1] = __builtin_amdgcn_mfma_f32_16x16x32_bf16(a0, b1, acc[0][1], 0, 0, 0);
    acc[1][0] = __builtin_amdgcn_mfma_f32_16x16x32_bf16(a1, b0, acc[1][0], 0, 0, 0);
    acc[1][1] = __builtin_amdgcn_mfma_f32_16x16x32_bf16(a1, b1, acc[1][1], 0, 0, 0);
    __syncthreads();
  }

  if (mode == 3) {
    float* Co = (float*)Cout;
#pragma unroll
    for (int mi = 0; mi < 2; ++mi)
#pragma unroll
      for (int ni = 0; ni < 2; ++ni)
#pragma unroll
        for (int i = 0; i < 4; ++i) {
          int gm = m0 + wm + mi * 16 + quad * 4 + i;
          int gn = n0 + wn + ni * 16 + lanem;
          Co[(size_t)gm * N + gn] = acc[mi][ni][i] + bias[gn];
        }
  } else if (mode <= 1) {
    u16* Co = (u16*)Cout;
#pragma unroll
    for (int mi = 0; mi < 2; ++mi)
#pragma unroll
      for (int ni = 0; ni < 2; ++ni)
#pragma unroll
        for (int i = 0; i < 4; ++i) {
          int gm = m0 + wm + mi * 16 + quad * 4 + i;
          int gn = n0 + wn + ni * 16 + lanem;
          int bb = gm >> 11, t = gm & (T_ - 1);
          int hh = gn >> 6, hd = gn & 63;
          Co[(((size_t)bb * H_ + hh) * T_ + t) * HD_ + hd] = f2bf(acc[mi][ni][i] + bias[gn]);
        }
  } else {  // mode 2: V -> [B,H,HD,T] via LDS transpose bounce
#pragma unroll
    for (int mi = 0; mi < 2; ++mi)
#pragma unroll
      for (int ni = 0; ni < 2; ++ni)
#pragma unroll
        for (int i = 0; i < 4; ++i) {
          int lm = wm + mi * 16 + quad * 4 + i;   // local t
          int ln = wn + ni * 16 + lanem;          // local hd
          Cs[lm * 72 + ln] = f2bf(acc[mi][ni][i] + bias[n0 + ln]);
        }
    __syncthreads();
    u16* Co = (u16*)Cout;
    int hh = n0 >> 6, bb = m0 >> 11, tl = m0 & (T_ - 1);
#pragma unroll
    for (int it = 0; it < 2; ++it) {
      int idx = it * 256 + tid;
      int hd = idx >> 3, cc = idx & 7;
      uint4 val;
      u16* vp = (u16*)&val;
#pragma unroll
      for (int j = 0; j < 8; ++j) vp[j] = Cs[(cc * 8 + j) * 72 + hd];
      *(uint4*)(Co + (((size_t)bb * H_ + hh) * HD_ + hd) * T_ + tl + cc * 8) = val;
    }
  }
}

// Flash attention: one block per (b, h, 64-row q tile). 4 waves, each owns 16 q rows.
__global__ __launch_bounds__(256)
void flash(const u16* __restrict__ qb, const u16* __restrict__ kb,
           const u16* __restrict__ vtb, u16* __restrict__ ob) {
  __shared__ u16 Qs[64 * 72];
  __shared__ u16 Ks[64 * 72];
  __shared__ u16 Vs[64 * 72];
  __shared__ u16 Ps[64 * 72];
  int tid = threadIdx.x;
  int qt0 = blockIdx.x * 64;
  int h = blockIdx.y, b = blockIdx.z;
  size_t bh = (size_t)b * H_ + h;
  const u16* Qg = qb + (bh * T_ + qt0) * HD_;
  const u16* Kg = kb + bh * T_ * HD_;
  const u16* Vg = vtb + bh * HD_ * T_;   // [hd][T]
  u16* Og = ob + ((size_t)b * T_ + qt0) * D_ + h * HD_;
  int wv = tid >> 6, lane = tid & 63, lanem = lane & 15, quad = lane >> 4;
  int qw0 = wv * 16;

#pragma unroll
  for (int it = 0; it < 2; ++it) {
    int idx = it * 256 + tid, r = idx >> 3, c = (idx & 7) * 8;
    *(uint4*)&Qs[r * 72 + c] = *(const uint4*)&Qg[r * HD_ + c];
  }

  f32x4 acc_o[4];
  float mrow[4], lrow[4];
#pragma unroll
  for (int ni = 0; ni < 4; ++ni) acc_o[ni] = (f32x4){0.f, 0.f, 0.f, 0.f};
#pragma unroll
  for (int i = 0; i < 4; ++i) { mrow[i] = -__builtin_inff(); lrow[i] = 0.f; }

  for (int s0 = 0; s0 <= qt0; s0 += 64) {
    __syncthreads();
#pragma unroll
    for (int it = 0; it < 2; ++it) {
      int idx = it * 256 + tid, r = idx >> 3, c = (idx & 7) * 8;
      *(uint4*)&Ks[r * 72 + c] = *(const uint4*)&Kg[(size_t)(s0 + r) * HD_ + c];
      *(uint4*)&Vs[r * 72 + c] = *(const uint4*)&Vg[(size_t)r * T_ + s0 + c];
    }
    __syncthreads();

    f32x4 accs[4];
#pragma unroll
    for (int ni = 0; ni < 4; ++ni) accs[ni] = (f32x4){0.f, 0.f, 0.f, 0.f};
#pragma unroll
    for (int ks = 0; ks < 2; ++ks) {
      bf16x8 aq = ld8(&Qs[(qw0 + lanem) * 72 + ks * 32 + quad * 8]);
#pragma unroll
      for (int ni = 0; ni < 4; ++ni) {
        bf16x8 bk8 = ld8(&Ks[(ni * 16 + lanem) * 72 + ks * 32 + quad * 8]);
        accs[ni] = __builtin_amdgcn_mfma_f32_16x16x32_bf16(aq, bk8, accs[ni], 0, 0, 0);
      }
    }

    bool diag = (s0 == qt0);
#pragma unroll
    for (int i = 0; i < 4; ++i) {
      int qg = qt0 + qw0 + quad * 4 + i;
      float vmax = -__builtin_inff();
#pragma unroll
      for (int ni = 0; ni < 4; ++ni) {
        float sv = accs[ni][i] * 0.125f;
        if (diag && (s0 + ni * 16 + lanem > qg)) sv = -__builtin_inff();
        accs[ni][i] = sv;
        vmax = fmaxf(vmax, sv);
      }
#pragma unroll
      for (int off = 1; off < 16; off <<= 1) vmax = fmaxf(vmax, __shfl_xor(vmax, off));
      float mnew = fmaxf(mrow[i], vmax);
      float alpha = __expf(mrow[i] - mnew);
      float rsum = 0.f;
#pragma unroll
      for (int ni = 0; ni < 4; ++ni) {
        float p = __expf(accs[ni][i] - mnew);
        rsum += p;
        Ps[(qw0 + quad * 4 + i) * 72 + ni * 16 + lanem] = f2bf(p);
      }
#pragma unroll
      for (int off = 1; off < 16; off <<= 1) rsum += __shfl_xor(rsum, off);
      lrow[i] = lrow[i] * alpha + rsum;
      mrow[i] = mnew;
#pragma unroll
      for (int ni = 0; ni < 4; ++ni) acc_o[ni][i] *= alpha;
    }
    __syncthreads();  // make Ps writes safely visible before A-frag reads

#pragma unroll
    for (int ks = 0; ks < 2; ++ks) {
      bf16x8 ap = ld8(&Ps[(qw0 + lanem) * 72 + ks * 32 + quad * 8]);
#pragma unroll
      for (int ni = 0; ni < 4; ++ni) {
        bf16x8 bv8 = ld8(&Vs[(ni * 16 + lanem) * 72 + ks * 32 + quad * 8]);
        acc_o[ni] = __builtin_amdgcn_mfma_f32_16x16x32_bf16(ap, bv8, acc_o[ni], 0, 0, 0);
      }
    }
  }

#pragma unroll
  for (int i = 0; i < 4; ++i) {
    float inv = 1.f / lrow[i];
#pragma unroll
    for (int ni = 0; ni < 4; ++ni) {
      Og[(size_t)(qw0 + quad * 4 + i) * D_ + ni * 16 + lanem] = f2bf(acc_o[ni][i] * inv);
    }
  }
}

extern "C" void kernel_launch(void* const* d_in, const int* in_sizes, int n_in,
                              void* d_out, int out_size, void* d_ws, size_t ws_size,
                              hipStream_t stream) {
  const float* x  = (const float*)d_in[0];
  const float* wq = (const float*)d_in[1];
  const float* bq = (const float*)d_in[2];
  const float* wk = (const float*)d_in[3];
  const float* bk = (const float*)d_in[4];
  const float* wv = (const float*)d_in[5];
  const float* bv = (const float*)d_in[6];
  const float* wo = (const float*)d_in[7];
  const float* bo = (const float*)d_in[8];
  // d_in[9] = causal mask, implemented analytically.

  char* ws = (char*)d_ws;
  const size_t MB = 1ull << 20;
  u16* xb  = (u16*)(ws + 0 * MB);    // [8192,1024] bf16   16 MiB
  u16* wqb = (u16*)(ws + 16 * MB);   // [1024,1024] bf16    2 MiB
  u16* wkb = (u16*)(ws + 18 * MB);
  u16* wvb = (u16*)(ws + 20 * MB);
  u16* wob = (u16*)(ws + 22 * MB);
  u16* qb  = (u16*)(ws + 24 * MB);   // [B,H,T,HD] bf16    16 MiB
  u16* kb  = (u16*)(ws + 40 * MB);   // [B,H,T,HD]
  u16* vtb = (u16*)(ws + 56 * MB);   // [B,H,HD,T]
  u16* ob  = (u16*)(ws + 72 * MB);   // [8192,1024] bf16

  cvt_bf16<<<M_ * D_ / 1024, 256, 0, stream>>>(x, xb, M_ * D_);
  cvt_bf16<<<D_ * D_ / 1024, 256, 0, stream>>>(wq, wqb, D_ * D_);
  cvt_bf16<<<D_ * D_ / 1024, 256, 0, stream>>>(wk, wkb, D_ * D_);
  cvt_bf16<<<D_ * D_ / 1024, 256, 0, stream>>>(wv, wvb, D_ * D_);
  cvt_bf16<<<D_ * D_ / 1024, 256, 0, stream>>>(wo, wob, D_ * D_);

  dim3 gg(D_ / 64, M_ / 64);
  gemm_bt<<<gg, 256, 0, stream>>>(xb, wqb, bq, qb, 0);
  gemm_bt<<<gg, 256, 0, stream>>>(xb, wkb, bk, kb, 1);
  gemm_bt<<<gg, 256, 0, stream>>>(xb, wvb, bv, vtb, 2);

  flash<<<dim3(T_ / 64, H_, B_), 256, 0, stream>>>(qb, kb, vtb, ob);

  gemm_bt<<<gg, 256, 0, stream>>>(ob, wob, bo, (float*)d_out, 3);
}